// Round 5
// baseline (119.243 us; speedup 1.0000x reference)
//
#include <hip/hip_runtime.h>

// QOuter: out_rr[b,i,j] = real[b,i]*real[b,j] + imag[b,i]*imag[b,j]
//         out_ii[b,i,j] = imag[b,i]*real[b,j] - real[b,i]*imag[b,j]
// B=64, N=1024. Outputs concatenated flat: [out_rr (B*N*N), out_ii (B*N*N)].
// Store-BW bound. This round: fill-mimic persistent kernel. 2048 blocks x 256
// threads grid-stride; each iteration the whole device writes one contiguous
// 8 MiB slab (like __amd_rocclr_fillBufferAligned, which sustains 6.7 TB/s).
// Per-thread i,j are loop-invariant; b advances by 2 per iter (wave-uniform).

typedef float f32x4 __attribute__((ext_vector_type(4)));

constexpr int B_ = 64;
constexpr int N_ = 1024;
constexpr int NBLK = 2048;
constexpr int NTHR = 256;
// total float4s = 2*B*N*N/4 = 33,554,432 ; threads = 524,288 ; iters = 64
constexpr size_t TOTAL_F4   = (size_t)2 * B_ * N_ * N_ / 4;   // 32 Mi
constexpr size_t GRID_THREADS = (size_t)NBLK * NTHR;          // 512 Ki
constexpr int    ITERS      = (int)(TOTAL_F4 / GRID_THREADS); // 64
constexpr size_t HALF_F4    = TOTAL_F4 / 2;                   // 16 Mi (rr count)

__global__ __launch_bounds__(NTHR) void qouter_kernel(
    const float* __restrict__ real,
    const float* __restrict__ imag,
    float* __restrict__ out) {
    const size_t gid = (size_t)blockIdx.x * NTHR + threadIdx.x;

    // Loop-invariant decode (stride = 2 batches' worth of float4s):
    const int b0 = (int)(gid >> 18);            // 0 or 1
    const int i  = (int)((gid & 262143) >> 8);  // row index, fixed per thread
    const int j4 = (int)(gid & 255);            // float4 col index, fixed

    f32x4* out4 = reinterpret_cast<f32x4*>(out);

#pragma unroll 4
    for (int k = 0; k < ITERS; ++k) {
        const int  b    = b0 + 2 * (k & 31);      // wave-uniform batch
        const bool iiH  = (k >= 32);              // second half -> out_ii
        const size_t f  = gid + (size_t)k * GRID_THREADS;

        const float* rrow = real + (size_t)b * N_;
        const float* irow = imag + (size_t)b * N_;
        const float rc = rrow[i];                  // wave-uniform, L2-hot
        const float ic = irow[i];
        const f32x4 rj = reinterpret_cast<const f32x4*>(rrow)[j4];
        const f32x4 ij = reinterpret_cast<const f32x4*>(irow)[j4];

        f32x4 o;
        if (!iiH) o = rc * rj + ic * ij;           // out_rr
        else      o = ic * rj - rc * ij;           // out_ii
        __builtin_nontemporal_store(o, out4 + f);
    }
}

extern "C" void kernel_launch(void* const* d_in, const int* in_sizes, int n_in,
                              void* d_out, int out_size, void* d_ws, size_t ws_size,
                              hipStream_t stream) {
    const float* real = (const float*)d_in[0];
    const float* imag = (const float*)d_in[1];
    float* out = (float*)d_out;

    qouter_kernel<<<dim3(NBLK), dim3(NTHR), 0, stream>>>(real, imag, out);
}

// Round 6
// 88.497 us; speedup vs baseline: 1.3474x; 1.3474x over previous
//
#include <hip/hip_runtime.h>

// QOuter: out_rr[b,i,j] = real[b,i]*real[b,j] + imag[b,i]*imag[b,j]
//         out_ii[b,i,j] = imag[b,i]*real[b,j] - real[b,i]*imag[b,j]
// B=64, N=1024. Outputs concatenated flat: [out_rr (B*N*N), out_ii (B*N*N)].
// Store-BW bound. Round 6: minimal work per thread — ONE 16B NT store each.
// Block = 512 threads = one (b,i) row pair: waves 0-3 write the rr row,
// waves 4-7 write the ii row (wave-uniform split). 32768 blocks.
// Trend so far: stores/thread 2->16->64 gave 100->103->119 us; this is the
// 1-store/thread extreme.

typedef float f32x4 __attribute__((ext_vector_type(4)));

constexpr int B_ = 64;
constexpr int N_ = 1024;

__global__ __launch_bounds__(512) void qouter_kernel(
    const float* __restrict__ real,
    const float* __restrict__ imag,
    float* __restrict__ out) {
    const int bi   = blockIdx.x;            // 0 .. B*N-1  (one block per row i)
    const int b    = bi >> 10;              // bi / N
    const int t    = threadIdx.x;
    const int half = t >> 8;                // 0: out_rr, 1: out_ii (wave-uniform)
    const int j4   = t & 255;               // float4 column index

    // Row scalars (block-uniform -> s_load) and row vectors (L1/L2-hot)
    const float rc = real[bi];
    const float ic = imag[bi];
    const f32x4 rj = reinterpret_cast<const f32x4*>(real + (size_t)b * N_)[j4];
    const f32x4 ij = reinterpret_cast<const f32x4*>(imag + (size_t)b * N_)[j4];

    const f32x4 o = half ? (ic * rj - rc * ij)    // out_ii
                         : (rc * rj + ic * ij);   // out_rr

    const size_t f4 = (size_t)bi * (N_ / 4) + j4
                    + (size_t)half * ((size_t)B_ * N_ * (N_ / 4));
    __builtin_nontemporal_store(o, reinterpret_cast<f32x4*>(out) + f4);
}

extern "C" void kernel_launch(void* const* d_in, const int* in_sizes, int n_in,
                              void* d_out, int out_size, void* d_ws, size_t ws_size,
                              hipStream_t stream) {
    const float* real = (const float*)d_in[0];
    const float* imag = (const float*)d_in[1];
    float* out = (float*)d_out;

    dim3 grid(B_ * N_);    // 65536 row-pairs? no: 65536 blocks, one per (b,i)
    dim3 block(512);       // 2 rows' worth of float4 stores (rr + ii)
    qouter_kernel<<<grid, block, 0, stream>>>(real, imag, out);
}